// Round 5
// baseline (149.649 us; speedup 1.0000x reference)
//
#include <hip/hip_runtime.h>
#include <hip/hip_bf16.h>
#include <stdint.h>

#define B_    4
#define NN    4096
#define DIN   512
#define DOUT  256
#define ALPHA_ 0.2f

typedef __attribute__((ext_vector_type(8))) short short8;
typedef __attribute__((ext_vector_type(4))) float f32x4;

typedef const __attribute__((address_space(1))) void gconst_void;
typedef __attribute__((address_space(3))) void lds_void;

__device__ __forceinline__ unsigned short f2bf(float x) {
    union { float f; uint32_t u; } v; v.f = x;
    uint32_t r = v.u + 0x7FFFu + ((v.u >> 16) & 1u);
    return (unsigned short)(r >> 16);
}

// ---------------- K_prep: h fp32->bf16 | Ws -> WsT bf16 ----------
__global__ __launch_bounds__(256) void k_prep(const float4* __restrict__ h4,
                                              const float* __restrict__ Ws,
                                              uint2* __restrict__ hb,
                                              unsigned short* __restrict__ wst) {
    const int gid = blockIdx.x;
    const int tid = threadIdx.x;
    if (gid < 8192) {                        // h -> bf16 (float4 granularity)
        int idx = gid * 256 + tid;
        float4 v = h4[idx];
        uint2 o;
        o.x = (uint32_t)f2bf(v.x) | ((uint32_t)f2bf(v.y) << 16);
        o.y = (uint32_t)f2bf(v.z) | ((uint32_t)f2bf(v.w) << 16);
        hb[idx] = o;
    } else {                                 // Ws (B,DIN,DOUT) -> WsT (B,DOUT,DIN)
        int idx = (gid - 8192) * 256 + tid;
        int k = idx & (DIN - 1);
        int o = (idx >> 9) & (DOUT - 1);
        int b = idx >> 17;
        wst[idx] = f2bf(Ws[((size_t)b * DIN + k) * DOUT + o]);
    }
}

// ---------------- K1: gemm (blocks 0..255) + adj-pack (blocks 256..8447) -----------
// gemm: WhT = (h@Ws)^T + e1/e2 -> exp tables A1 (f32x2 per n) and XY (bf16x2 per m)
__global__ __launch_bounds__(256) void k_gemm1(const unsigned short* __restrict__ hb,
                                               const unsigned short* __restrict__ wst,
                                               const float* __restrict__ a,
                                               const int* __restrict__ adj,
                                               unsigned short* __restrict__ wht,
                                               float2* __restrict__ a1t,
                                               uint32_t* __restrict__ xyt,
                                               uint32_t* __restrict__ bits) {
    const int tid = threadIdx.x;
    if (blockIdx.x >= 256) {                 // ---- adj pack: 2048 ints per block ----
        const int base = (blockIdx.x - 256) * 2048;
        #pragma unroll
        for (int k = 0; k < 8; ++k) {
            int idx = base + k * 256 + tid;
            unsigned long long m = __ballot(adj[idx] > 0);
            if ((tid & 63) == 0)
                *reinterpret_cast<unsigned long long*>(bits + ((idx >> 6) << 1)) = m;
        }
        return;
    }
    __shared__ unsigned short Ah[64 * 64];    // [n][k] swizzled rows (128B)
    __shared__ unsigned short Bw[256 * 64];   // [d][k] swizzled rows (128B)
    __shared__ float e1s[64], e2s[64];
    const int w = tid >> 6, lane = tid & 63;
    const int l15 = lane & 15, lhi = lane >> 4;
    const int b = blockIdx.x >> 6;
    const int n0 = (blockIdx.x & 63) << 6;
    const unsigned short* hrow = hb + ((size_t)b * NN + n0) * DIN;
    const unsigned short* wrow = wst + (size_t)b * DOUT * DIN;

    if (tid < 64) { e1s[tid] = 0.f; e2s[tid] = 0.f; }

    f32x4 acc[4][4] = {};

    for (int kt = 0; kt < DIN / 64; ++kt) {
        const int k0 = kt * 64;
        #pragma unroll
        for (int it = 0; it < 2; ++it) {     // stage A: 8KB
            int q = it * 256 + tid;
            int row = q >> 3, c = q & 7;
            const unsigned short* src = hrow + (size_t)row * DIN + k0 + 8 * (c ^ (row & 7));
            char* dst = reinterpret_cast<char*>(Ah) + it * 4096 + w * 1024;
            __builtin_amdgcn_global_load_lds((gconst_void*)src, (lds_void*)dst, 16, 0, 0);
        }
        #pragma unroll
        for (int it = 0; it < 8; ++it) {     // stage B: 32KB
            int q = it * 256 + tid;
            int row = q >> 3, c = q & 7;
            const unsigned short* src = wrow + (size_t)row * DIN + k0 + 8 * (c ^ (row & 7));
            char* dst = reinterpret_cast<char*>(Bw) + it * 4096 + w * 1024;
            __builtin_amdgcn_global_load_lds((gconst_void*)src, (lds_void*)dst, 16, 0, 0);
        }
        __syncthreads();
        #pragma unroll
        for (int kk = 0; kk < 2; ++kk) {
            short8 af[4], bfr[4];
            #pragma unroll
            for (int rf = 0; rf < 4; ++rf) {
                int row = rf * 16 + l15;
                int off = row * 128 + ((kk * 64 + lhi * 16) ^ ((row & 7) << 4));
                af[rf] = *reinterpret_cast<const short8*>(reinterpret_cast<const char*>(Ah) + off);
            }
            #pragma unroll
            for (int cf = 0; cf < 4; ++cf) {
                int row = w * 64 + cf * 16 + l15;
                int off = row * 128 + ((kk * 64 + lhi * 16) ^ ((row & 7) << 4));
                bfr[cf] = *reinterpret_cast<const short8*>(reinterpret_cast<const char*>(Bw) + off);
            }
            #pragma unroll
            for (int rf = 0; rf < 4; ++rf)
                #pragma unroll
                for (int cf = 0; cf < 4; ++cf)
                    acc[rf][cf] = __builtin_amdgcn_mfma_f32_16x16x32_bf16(af[rf], bfr[cf], acc[rf][cf], 0, 0, 0);
        }
        __syncthreads();
    }
    // WhT write (bf16, transposed)
    unsigned short* wb = wht + (size_t)b * DOUT * NN;
    #pragma unroll
    for (int rf = 0; rf < 4; ++rf) {
        #pragma unroll
        for (int cf = 0; cf < 4; ++cf) {
            int d = w * 64 + cf * 16 + l15;
            int m = n0 + rf * 16 + lhi * 4;
            uint2 pk;
            pk.x = (uint32_t)f2bf(acc[rf][cf][0]) | ((uint32_t)f2bf(acc[rf][cf][1]) << 16);
            pk.y = (uint32_t)f2bf(acc[rf][cf][2]) | ((uint32_t)f2bf(acc[rf][cf][3]) << 16);
            *reinterpret_cast<uint2*>(wb + (size_t)d * NN + m) = pk;
        }
    }
    // fused e1/e2 via shfl-reduce over the 16-lane fragment columns
    const float* ab = a + b * 2 * DOUT;
    float a1v[4], a2v[4];
    #pragma unroll
    for (int cf = 0; cf < 4; ++cf) {
        int d = w * 64 + cf * 16 + l15;
        a1v[cf] = ab[d];
        a2v[cf] = ab[DOUT + d];
    }
    #pragma unroll
    for (int rf = 0; rf < 4; ++rf) {
        #pragma unroll
        for (int j = 0; j < 4; ++j) {
            float p1 = 0.f, p2 = 0.f;
            #pragma unroll
            for (int cf = 0; cf < 4; ++cf) {
                p1 = fmaf(acc[rf][cf][j], a1v[cf], p1);
                p2 = fmaf(acc[rf][cf][j], a2v[cf], p2);
            }
            #pragma unroll
            for (int msk = 1; msk < 16; msk <<= 1) {
                p1 += __shfl_xor(p1, msk);
                p2 += __shfl_xor(p2, msk);
            }
            if (l15 == 0) {
                atomicAdd(&e1s[rf * 16 + lhi * 4 + j], p1);
                atomicAdd(&e2s[rf * 16 + lhi * 4 + j], p2);
            }
        }
    }
    __syncthreads();
    if (tid < 64) {
        float e1v = e1s[tid], e2v = e2s[tid];
        a1t[b * NN + n0 + tid] = float2{__expf(e1v), __expf(ALPHA_ * e1v)};
        xyt[b * NN + n0 + tid] =
            (uint32_t)f2bf(__expf(e2v)) | ((uint32_t)f2bf(__expf(ALPHA_ * e2v)) << 16);
    }
}

// ---------------- K4: h' = softmax(P)@Wh via exp-tables, no TRANS in inner loop ----
// block: 64 n-rows x 128 d-cols, 4 waves (2n x 2d) each 32n x 64d (acc 2x4)
// LDS 48KB -> 3 blocks/CU. P = max(A*X[m], Bc*Y[m]) masked; psum in-loop.
__global__ __launch_bounds__(256, 3) void k_attn(const unsigned short* __restrict__ wht,
                                                 const uint32_t* __restrict__ bits,
                                                 const float2* __restrict__ a1t,
                                                 const uint32_t* __restrict__ xyt,
                                                 float* __restrict__ out) {
    __shared__ unsigned short Bw[2 * 128 * 64];  // WhT tile dbuf, swizzled rows (32KB)
    __shared__ unsigned short Pt[2 * 64 * 64];   // P tile dbuf, swizzled rows (16KB)
    float* sumsF = reinterpret_cast<float*>(Pt); // overlay after K-loop

    const int tid = threadIdx.x;
    const int w = tid >> 6, lane = tid & 63;
    const int l15 = lane & 15, lhi = lane >> 4;
    const int wn = w >> 1, wd = w & 1;

    // XCD-aware bijective swizzle: 512 blocks
    const int bid = blockIdx.x;
    const int wg = ((bid & 7) << 6) | (bid >> 3);
    const int b  = wg >> 7;
    const int r  = wg & 127;
    const int d0 = (r & 1) << 7;
    const int n0 = (r >> 1) << 6;

    // P mapping: pr = row (0..63), pc = 16-m group (0..3)
    const int pr = tid >> 2, pc = tid & 3;
    const int gn = n0 + pr;
    const float2 a1v = a1t[b * NN + gn];
    const float Af = a1v.x, Bc = a1v.y;
    const uint8_t* browb = reinterpret_cast<const uint8_t*>(bits) + (size_t)gn * (NN / 8);
    const uint32_t* xyg = xyt + b * NN;
    const unsigned short* wb = wht + (size_t)b * DOUT * NN;

    f32x4 acc[2][4] = {};
    float psum = 0.f;

    // P-compute macro body: 16 values from 4 uint4 of packed bf16 {X,Y}
#define P_COMPUTE(XQ, BB, DSTBASE)                                                    \
    {                                                                                 \
        float pv[16];                                                                 \
        _Pragma("unroll")                                                             \
        for (int i = 0; i < 4; ++i) {                                                 \
            _Pragma("unroll")                                                         \
            for (int k = 0; k < 4; ++k) {                                             \
                uint32_t wrd = XQ[i][k];                                              \
                int j = i * 4 + k;                                                    \
                union { uint32_t u; float f; } xf, yf;                                \
                xf.u = wrd << 16;                                                     \
                yf.u = wrd & 0xffff0000u;                                             \
                float p = fmaxf(Af * xf.f, Bc * yf.f);                                \
                uint32_t msk = (uint32_t)(((int32_t)(BB << (31 - j))) >> 31);         \
                union { float f; uint32_t u; } pu; pu.f = p; pu.u &= msk;             \
                pv[j] = pu.f;                                                         \
                psum += pv[j];                                                        \
            }                                                                         \
        }                                                                             \
        union { short8 v; uint32_t u[4]; } q0, q1;                                    \
        _Pragma("unroll")                                                             \
        for (int i = 0; i < 4; ++i) {                                                 \
            union { __hip_bfloat162 h; uint32_t u; } c0, c1;                          \
            c0.h = __float22bfloat162_rn(float2{pv[2 * i], pv[2 * i + 1]});           \
            c1.h = __float22bfloat162_rn(float2{pv[8 + 2 * i], pv[8 + 2 * i + 1]});   \
            q0.u[i] = c0.u; q1.u[i] = c1.u;                                           \
        }                                                                             \
        char* pb = (DSTBASE);                                                         \
        *reinterpret_cast<short8*>(pb + pr * 128 + ((pc * 32)      ^ ((pr & 7) << 4))) = q0.v; \
        *reinterpret_cast<short8*>(pb + pr * 128 + ((pc * 32 + 16) ^ ((pr & 7) << 4))) = q1.v; \
    }

    // ---- prologue: stage tile 0, compute P(0) ----
    #pragma unroll
    for (int it = 0; it < 4; ++it) {
        int q = it * 256 + tid;
        int row = q >> 3, c = q & 7;
        const unsigned short* src = wb + (size_t)(d0 + row) * NN + 8 * (c ^ (row & 7));
        char* dst = reinterpret_cast<char*>(Bw) + it * 4096 + w * 1024;
        __builtin_amdgcn_global_load_lds((gconst_void*)src, (lds_void*)dst, 16, 0, 0);
    }
    {
        uint32_t bb = *reinterpret_cast<const unsigned short*>(browb + pc * 2);
        const uint4* xp = reinterpret_cast<const uint4*>(xyg + pc * 16);
        uint4 xq[4] = {xp[0], xp[1], xp[2], xp[3]};
        P_COMPUTE(xq, bb, reinterpret_cast<char*>(Pt))
    }
    __syncthreads();

    // ---- main loop: 1 barrier/tile; stage(t+1)+XY(t+1) overlap MFMA(t) ----
    #pragma unroll 2
    for (int t = 0; t < NN / 64; ++t) {
        const int cur = t & 1;
        uint32_t bbN = 0;
        uint4 xq[4];
        if (t < NN / 64 - 1) {
            const int m1 = (t + 1) * 64;
            #pragma unroll
            for (int it = 0; it < 4; ++it) {
                int q = it * 256 + tid;
                int row = q >> 3, c = q & 7;
                const unsigned short* src = wb + (size_t)(d0 + row) * NN + m1 + 8 * (c ^ (row & 7));
                char* dst = reinterpret_cast<char*>(Bw) + (cur ^ 1) * 16384 + it * 4096 + w * 1024;
                __builtin_amdgcn_global_load_lds((gconst_void*)src, (lds_void*)dst, 16, 0, 0);
            }
            bbN = *reinterpret_cast<const unsigned short*>(browb + (m1 >> 3) + pc * 2);
            const uint4* xp = reinterpret_cast<const uint4*>(xyg + m1 + pc * 16);
            xq[0] = xp[0]; xq[1] = xp[1]; xq[2] = xp[2]; xq[3] = xp[3];
        }
        // MFMA phase on buffers [cur]
        __builtin_amdgcn_s_setprio(1);
        #pragma unroll
        for (int kk = 0; kk < 2; ++kk) {
            short8 af[2], bfr[4];
            #pragma unroll
            for (int rf = 0; rf < 2; ++rf) {
                int row = wn * 32 + rf * 16 + l15;
                int off = row * 128 + ((kk * 64 + lhi * 16) ^ ((row & 7) << 4));
                af[rf] = *reinterpret_cast<const short8*>(
                    reinterpret_cast<const char*>(Pt) + cur * 8192 + off);
            }
            #pragma unroll
            for (int cf = 0; cf < 4; ++cf) {
                int row = wd * 64 + cf * 16 + l15;
                int off = row * 128 + ((kk * 64 + lhi * 16) ^ ((row & 7) << 4));
                bfr[cf] = *reinterpret_cast<const short8*>(
                    reinterpret_cast<const char*>(Bw) + cur * 16384 + off);
            }
            #pragma unroll
            for (int rf = 0; rf < 2; ++rf)
                #pragma unroll
                for (int cf = 0; cf < 4; ++cf)
                    acc[rf][cf] = __builtin_amdgcn_mfma_f32_16x16x32_bf16(af[rf], bfr[cf], acc[rf][cf], 0, 0, 0);
        }
        __builtin_amdgcn_s_setprio(0);
        if (t < NN / 64 - 1) {
            P_COMPUTE(xq, bbN, reinterpret_cast<char*>(Pt) + (cur ^ 1) * 8192)
            __syncthreads();
        }
    }
#undef P_COMPUTE
    // ---- epilogue: row-sum -> reciprocal (Pt overlay), ELU, store ----
    psum += __shfl_xor(psum, 1);
    psum += __shfl_xor(psum, 2);
    __syncthreads();                   // all waves past final MFMA reads of Pt[0]
    if ((tid & 3) == 0) sumsF[pr] = 1.0f / psum;
    __syncthreads();
    #pragma unroll
    for (int rf = 0; rf < 2; ++rf) {
        #pragma unroll
        for (int cf = 0; cf < 4; ++cf) {
            int d = d0 + wd * 64 + cf * 16 + l15;
            #pragma unroll
            for (int j = 0; j < 4; ++j) {
                int lr = wn * 32 + rf * 16 + lhi * 4 + j;
                float x = acc[rf][cf][j] * sumsF[lr];
                x = x > 0.f ? x : (__expf(x) - 1.f);
                out[((size_t)b * NN + n0 + lr) * DOUT + d] = x;
            }
        }
    }
}

extern "C" void kernel_launch(void* const* d_in, const int* in_sizes, int n_in,
                              void* d_out, int out_size, void* d_ws, size_t ws_size,
                              hipStream_t stream) {
    (void)in_sizes; (void)n_in; (void)out_size; (void)ws_size;
    const float* h   = (const float*)d_in[0];
    const int*   adj = (const int*)d_in[1];
    const float* Ws  = (const float*)d_in[2];
    const float* a   = (const float*)d_in[3];
    float* out = (float*)d_out;

    char* ws = (char*)d_ws;
    unsigned short* hb  = (unsigned short*)(ws);              // 16,777,216 B
    unsigned short* wst = (unsigned short*)(ws + 16777216);   //  1,048,576 B
    unsigned short* wht = (unsigned short*)(ws + 17825792);   //  8,388,608 B
    float2*   a1t = (float2*)(ws + 26214400);                 //    131,072 B
    uint32_t* xyt = (uint32_t*)(ws + 26345472);               //     65,536 B
    uint32_t* bits = (uint32_t*)(ws + 26476544);              //  2,097,152 B

    k_prep<<<dim3(10240), dim3(256), 0, stream>>>((const float4*)h, Ws, (uint2*)hb, wst);
    k_gemm1<<<dim3(256 + 8192), dim3(256), 0, stream>>>(hb, wst, a, adj, wht, a1t, xyt, bits);
    k_attn<<<dim3(512), dim3(256), 0, stream>>>(wht, bits, a1t, xyt, out);
}